// Round 9
// baseline (219.906 us; speedup 1.0000x reference)
//
#include <hip/hip_runtime.h>
#include <hip/hip_bf16.h>

typedef __bf16 bf16;
typedef __bf16 bf16x8 __attribute__((ext_vector_type(8)));
typedef __bf16 bf16x4 __attribute__((ext_vector_type(4)));
typedef float f32x4 __attribute__((ext_vector_type(4)));
typedef unsigned short ushort4v __attribute__((ext_vector_type(4)));

#define HID 1024
#define SEQL 2048
#define NB 4

#define AS1 __attribute__((address_space(1)))
#define AS3 __attribute__((address_space(3)))

// ---------------- fused fp32 -> bf16 cast (x, Wq, Wk, Wv, Wo) + bias concat ----------------
__global__ __launch_bounds__(256) void cast_all(const float* __restrict__ x,
    const float* __restrict__ Wq, const float* __restrict__ Wk,
    const float* __restrict__ Wv, const float* __restrict__ Wo,
    const float* __restrict__ bq, const float* __restrict__ bk, const float* __restrict__ bv,
    bf16* __restrict__ XB, bf16* __restrict__ WQKVB, bf16* __restrict__ WOB,
    float* __restrict__ bqkv) {
  const int b = blockIdx.x;
  if (b >= 12288) {  // 12 blocks: concat q/k/v biases [3072]
    const int i = (b - 12288) * 256 + threadIdx.x;
    bqkv[i] = (i < HID) ? bq[i] : (i < 2 * HID ? bk[i - HID] : bv[i - 2 * HID]);
    return;
  }
  const float* src; bf16* dst; long base;
  if (b < 8192) { src = x; dst = XB; base = (long)b * 256; }
  else {
    const int w = (b - 8192) >> 10, r = (b - 8192) & 1023;
    src = (w == 0) ? Wq : (w == 1) ? Wk : (w == 2) ? Wv : Wo;
    dst = (w == 3) ? WOB : WQKVB + (long)w * (HID * HID);
    base = (long)r * 256;
  }
  const long i = base + threadIdx.x;
  float4 v = reinterpret_cast<const float4*>(src)[i];
  bf16x4 o = { (bf16)v.x, (bf16)v.y, (bf16)v.z, (bf16)v.w };
  reinterpret_cast<bf16x4*>(dst)[i] = o;
}

// ---------------- NT GEMM: 256x256 tile, BK=64, 8 waves (2M x 4N) of 128x64 ----------------
// 4 dual-barrier phases per K64-tile (quadrants Q(m_lo,n_lo)->(m_lo,n_hi)->(m_hi,n_hi)->
// (m_hi,n_lo), frags reused across phases: 24 ds_read_b128 / 64 MFMA per wave per tile).
// LDS 2 x 64KB buffers (A: 4 chunks 64rx64k, B: 4 chunks 64nx64k; chunk row XOR-swizzle
// on 16B slots, applied inverse on global src, forward on reads -> <=2-way conflicts).
// Stage: 2 x 8KB gload_lds per phase; B(T+1) at p1/p2, A(T+2) at p3/p4 (WAR-safe:
// each chunk's replacement >=1 barrier after its last read). vmcnt(4) at p4 retires
// exactly through tile T+1's loads; tail: vmcnt(0). 1 block/CU.
template <typename OutT, bool BIAS, bool CSKIP, bool KLIM, bool EXPP, bool RSDIV, bool QKVSC, bool SWZ>
__global__ __launch_bounds__(512, 2)
void gemm_nt(const bf16* __restrict__ A, const bf16* __restrict__ B,
             const float* __restrict__ bias, OutT* __restrict__ C,
             int K, int lda, int ldb, int N, long sA, long sB, long sC) {
  int bj, bi;
  if (SWZ) {
    const int lin = blockIdx.x + gridDim.x * blockIdx.y;
    const int chunk = (gridDim.x * gridDim.y) >> 3;
    const int lg = (lin & 7) * chunk + (lin >> 3);
    bj = lg % gridDim.x; bi = lg / gridDim.x;
  } else { bj = blockIdx.x; bi = blockIdx.y; }
  const int bz = blockIdx.z;
  if (CSKIP && bj > bi) return;  // fully-masked causal 256-block
  A += (long)bz * sA + (long)bi * 256 * lda;
  B += (long)bz * sB + (long)bj * 256 * ldb;
  const int nt = (KLIM ? ((bi + 1) * 256) : K) >> 6;  // >= 4 always

  __shared__ bf16 lds[2][32768];  // 2 x 64 KiB

  const int t = threadIdx.x;
  const int lane = t & 63, wid = t >> 6;
  const int wm = wid >> 2, wn = wid & 3;   // wave tile: rows [wm*128,+128), cols [wn*64,+64)
  const int frow = lane & 15, l4 = lane >> 4;

  const int srow = t >> 3;                          // stage chunk-row 0..63
  const int scol = (((t & 7) ^ (srow & 7)) << 3);   // inverse-swizzled src col (elems)

  // read offsets (elements): A chunk=4096 elems, row stride 64, slot=8 elems
  int offA[4][2], offB[2][2];
#pragma unroll
  for (int m = 0; m < 4; ++m) {
    const int inrow = m * 16 + frow;
#pragma unroll
    for (int kh = 0; kh < 2; ++kh)
      offA[m][kh] = (wm * 2) * 4096 + inrow * 64 + ((((kh << 2) + l4) ^ (frow & 7)) << 3);
  }
#pragma unroll
  for (int n = 0; n < 2; ++n) {
    const int incol = n * 16 + frow;
#pragma unroll
    for (int kh = 0; kh < 2; ++kh)
      offB[n][kh] = 16384 + wn * 4096 + incol * 64 + ((((kh << 2) + l4) ^ (frow & 7)) << 3);
  }
  // m+4 frags: +4096 elems (next A chunk); n+2 frags: +2048 elems (rows 32-63 of B chunk)

  f32x4 acc[8][4] = {};

#define STG_A(buf, T, c)                                                                  \
  if ((T) < nt) {                                                                         \
    __builtin_amdgcn_global_load_lds(                                                     \
        (const AS1 void*)(A + (long)((c) * 64 + srow) * lda + ((T) << 6) + scol),         \
        (AS3 void*)(&lds[buf][(c) * 4096 + t * 8]), 16, 0, 0);                            \
  }
#define STG_B(buf, T, c)                                                                  \
  if ((T) < nt) {                                                                         \
    __builtin_amdgcn_global_load_lds(                                                     \
        (const AS1 void*)(B + (long)((c) * 64 + srow) * ldb + ((T) << 6) + scol),         \
        (AS3 void*)(&lds[buf][16384 + (c) * 4096 + t * 8]), 16, 0, 0);                    \
  }

  // prologue: tile0 (8 loads) + tile1 A (4 loads); wait tile0 -> 4 outstanding
  STG_A(0, 0, 0); STG_A(0, 0, 1); STG_A(0, 0, 2); STG_A(0, 0, 3);
  STG_B(0, 0, 0); STG_B(0, 0, 1); STG_B(0, 0, 2); STG_B(0, 0, 3);
  STG_A(1, 1, 0); STG_A(1, 1, 1); STG_A(1, 1, 2); STG_A(1, 1, 3);
  asm volatile("s_waitcnt vmcnt(4)" ::: "memory");
  __builtin_amdgcn_s_barrier();

  for (int T = 0; T < nt; ++T) {
    const bf16* lb = &lds[T & 1][0];
    const int nb = (T & 1) ^ 1;
    bf16x8 a[4][2], b0[2][2], b1[2][2];

    // ---- phase 1: Q(m_lo, n_lo). 12 reads; stage B0,B1(T+1)
#pragma unroll
    for (int m = 0; m < 4; ++m)
#pragma unroll
      for (int kh = 0; kh < 2; ++kh)
        a[m][kh] = *reinterpret_cast<const bf16x8*>(lb + offA[m][kh]);
#pragma unroll
    for (int n = 0; n < 2; ++n)
#pragma unroll
      for (int kh = 0; kh < 2; ++kh)
        b0[n][kh] = *reinterpret_cast<const bf16x8*>(lb + offB[n][kh]);
    STG_B(nb, T + 1, 0); STG_B(nb, T + 1, 1);
    asm volatile("s_waitcnt lgkmcnt(8)" ::: "memory");
    __builtin_amdgcn_sched_barrier(0);
    __builtin_amdgcn_s_barrier();
    asm volatile("s_waitcnt lgkmcnt(0)" ::: "memory");
    __builtin_amdgcn_sched_barrier(0);
    __builtin_amdgcn_s_setprio(1);
#pragma unroll
    for (int m = 0; m < 4; ++m)
#pragma unroll
      for (int n = 0; n < 2; ++n)
#pragma unroll
        for (int kh = 0; kh < 2; ++kh)
          acc[m][n] = __builtin_amdgcn_mfma_f32_16x16x32_bf16(a[m][kh], b0[n][kh], acc[m][n], 0, 0, 0);
    __builtin_amdgcn_s_setprio(0);
    __builtin_amdgcn_sched_barrier(0);
    __builtin_amdgcn_s_barrier();

    // ---- phase 2: Q(m_lo, n_hi). 4 reads; stage B2,B3(T+1)
#pragma unroll
    for (int n = 0; n < 2; ++n)
#pragma unroll
      for (int kh = 0; kh < 2; ++kh)
        b1[n][kh] = *reinterpret_cast<const bf16x8*>(lb + offB[n][kh] + 2048);
    STG_B(nb, T + 1, 2); STG_B(nb, T + 1, 3);
    __builtin_amdgcn_sched_barrier(0);
    __builtin_amdgcn_s_barrier();
    asm volatile("s_waitcnt lgkmcnt(0)" ::: "memory");
    __builtin_amdgcn_sched_barrier(0);
    __builtin_amdgcn_s_setprio(1);
#pragma unroll
    for (int m = 0; m < 4; ++m)
#pragma unroll
      for (int n = 0; n < 2; ++n)
#pragma unroll
        for (int kh = 0; kh < 2; ++kh)
          acc[m][2 + n] = __builtin_amdgcn_mfma_f32_16x16x32_bf16(a[m][kh], b1[n][kh], acc[m][2 + n], 0, 0, 0);
    __builtin_amdgcn_s_setprio(0);
    __builtin_amdgcn_sched_barrier(0);
    __builtin_amdgcn_s_barrier();

    // ---- phase 3: Q(m_hi, n_hi). 8 reads (A m4-7 overwrite a[]); stage A0,A2(T+2)
#pragma unroll
    for (int m = 0; m < 4; ++m)
#pragma unroll
      for (int kh = 0; kh < 2; ++kh)
        a[m][kh] = *reinterpret_cast<const bf16x8*>(lb + offA[m][kh] + 4096);
    STG_A(T & 1, T + 2, 0); STG_A(T & 1, T + 2, 2);
    __builtin_amdgcn_sched_barrier(0);
    __builtin_amdgcn_s_barrier();
    asm volatile("s_waitcnt lgkmcnt(0)" ::: "memory");
    __builtin_amdgcn_sched_barrier(0);
    __builtin_amdgcn_s_setprio(1);
#pragma unroll
    for (int m = 0; m < 4; ++m)
#pragma unroll
      for (int n = 0; n < 2; ++n)
#pragma unroll
        for (int kh = 0; kh < 2; ++kh)
          acc[4 + m][2 + n] = __builtin_amdgcn_mfma_f32_16x16x32_bf16(a[m][kh], b1[n][kh], acc[4 + m][2 + n], 0, 0, 0);
    __builtin_amdgcn_s_setprio(0);
    __builtin_amdgcn_sched_barrier(0);
    __builtin_amdgcn_s_barrier();

    // ---- phase 4: Q(m_hi, n_lo). 0 reads; stage A1,A3(T+2); tile-boundary vmcnt
    STG_A(T & 1, T + 2, 1); STG_A(T & 1, T + 2, 3);
    __builtin_amdgcn_sched_barrier(0);
    __builtin_amdgcn_s_barrier();
    __builtin_amdgcn_s_setprio(1);
#pragma unroll
    for (int m = 0; m < 4; ++m)
#pragma unroll
      for (int n = 0; n < 2; ++n)
#pragma unroll
        for (int kh = 0; kh < 2; ++kh)
          acc[4 + m][n] = __builtin_amdgcn_mfma_f32_16x16x32_bf16(a[m][kh], b0[n][kh], acc[4 + m][n], 0, 0, 0);
    __builtin_amdgcn_s_setprio(0);
    __builtin_amdgcn_sched_barrier(0);
    if (T + 2 < nt)      { asm volatile("s_waitcnt vmcnt(4)" ::: "memory"); }
    else if (T + 1 < nt) { asm volatile("s_waitcnt vmcnt(0)" ::: "memory"); }
    __builtin_amdgcn_s_barrier();
  }
#undef STG_A
#undef STG_B

  // epilogue: C/D frag layout col=lane&15, row=(lane>>4)*4+rr
  const int crow = l4 * 4;
  const int ccol = frow;
#pragma unroll
  for (int m = 0; m < 8; ++m) {
#pragma unroll
    for (int n = 0; n < 4; ++n) {
      const int coll = wn * 64 + n * 16 + ccol;
      const int colg = bj * 256 + coll;
      const float bv = BIAS ? bias[colg] : 0.0f;
      const float sc = QKVSC ? (colg < HID ? 0.03125f : 1.0f) : 1.0f;
      const int rbase = wm * 128 + m * 16 + crow;
#pragma unroll
      for (int rr = 0; rr < 4; ++rr) {
        const long row = (long)bi * 256 + rbase + rr;
        float v = acc[m][n][rr];
        if (EXPP)  v = (colg <= row) ? __expf(v) : 0.0f;  // causal mask + max-free exp
        else       v = (v + bv) * sc;
        if (RSDIV) v *= bias[(long)bz * SEQL + row];      // 1/rowsum, per batch
        C[(long)bz * sC + row * N + colg] = (OutT)v;
      }
    }
  }
}

// ---------------- row sums of P' -> inverse (wave per row) ----------------
__global__ __launch_bounds__(256) void rowsum_inv(const bf16* __restrict__ P,
                                                  float* __restrict__ RS) {
  const int lane = threadIdx.x & 63;
  const int wid = threadIdx.x >> 6;
  const long row = (long)blockIdx.x * 4 + wid;  // 0 .. 8191
  const int i = (int)(row & (SEQL - 1));
  const int kend = i | 255;  // written region (256-granular)
  const bf16* src = P + row * SEQL;
  float s = 0.f;
#pragma unroll
  for (int c = 0; c < 4; ++c) {
    const int j0 = c * 512 + lane * 8;
    if (j0 <= kend) {
      bf16x8 v = *reinterpret_cast<const bf16x8*>(src + j0);
#pragma unroll
      for (int j = 0; j < 8; ++j) s += (float)v[j];
    }
  }
#pragma unroll
  for (int off = 32; off > 0; off >>= 1) s += __shfl_xor(s, off);
  if (lane == 0) RS[row] = 1.0f / s;
}

// ---------------- bf16 64x64 tiled transpose: V[b][s][h] (stride ldv) -> VT[b][h][s] ----------------
__global__ __launch_bounds__(256) void transpose64(const bf16* __restrict__ V,
                                                   bf16* __restrict__ VT, int ldv) {
  __shared__ bf16 tile[64][72];
  const int b = blockIdx.z;
  const int s0 = blockIdx.x * 64;
  const int h0 = blockIdx.y * 64;
  const int t = threadIdx.x;
  const int r = t >> 4;
  const int c = (t & 15) * 4;
  const bf16* src = V + ((long)b * SEQL + s0) * ldv + h0;
#pragma unroll
  for (int rr = 0; rr < 4; ++rr) {
    const int row = r + rr * 16;
    *reinterpret_cast<ushort4v*>(&tile[row][c]) =
        *reinterpret_cast<const ushort4v*>(src + (long)row * ldv + c);
  }
  __syncthreads();
  bf16* dst = VT + ((long)b * HID + h0) * SEQL + s0;
#pragma unroll
  for (int rr = 0; rr < 4; ++rr) {
    const int hr = r + rr * 16;
    bf16x4 o = { tile[c + 0][hr], tile[c + 1][hr], tile[c + 2][hr], tile[c + 3][hr] };
    *reinterpret_cast<bf16x4*>(dst + (long)hr * SEQL + c) = o;
  }
}

extern "C" void kernel_launch(void* const* d_in, const int* in_sizes, int n_in,
                              void* d_out, int out_size, void* d_ws, size_t ws_size,
                              hipStream_t stream) {
  const float* x  = (const float*)d_in[0];
  const float* Wq = (const float*)d_in[1];
  const float* bq = (const float*)d_in[2];
  const float* Wk = (const float*)d_in[3];
  const float* bk = (const float*)d_in[4];
  const float* Wv = (const float*)d_in[5];
  const float* bv = (const float*)d_in[6];
  const float* Wo = (const float*)d_in[7];
  const float* bo = (const float*)d_in[8];
  float* out = (float*)d_out;

  // workspace (~136.4 MiB), lifetime-safe aliasing (as R8):
  char* ws = (char*)d_ws;
  bf16*  XB    = (bf16*)(ws);
  bf16*  WQKVB = (bf16*)(ws + 16777216L);
  float* bqkv  = (float*)(ws + 23068672L);
  bf16*  QKV   = (bf16*)(ws + 33554432L);
  bf16*  CTX   = (bf16*)(ws + 33554432L);
  bf16*  VT    = (bf16*)(ws + 83886080L);
  bf16*  WOB   = (bf16*)(ws + 100663296L);
  bf16*  P     = (bf16*)(ws + 102760448L);
  float* RS    = (float*)(ws + 136314880L);

  // 1) fused casts + bias concat
  cast_all<<<12300, 256, 0, stream>>>(x, Wq, Wk, Wv, Wo, bq, bk, bv, XB, WQKVB, WOB, bqkv);

  // 2) QKV projection: [8192,1024] x [3072,1024]^T; q-cols scaled 1/32 (XCD-swizzled)
  gemm_nt<bf16, true, false, false, false, false, true, true><<<dim3(12, 32, 1), 512, 0, stream>>>(
      XB, WQKVB, bqkv, QKV, HID, HID, HID, 3 * HID, 0, 0, 0);

  // 3) v -> vT (per batch)
  transpose64<<<dim3(SEQL / 64, HID / 64, NB), 256, 0, stream>>>(QKV + 2 * HID, VT, 3 * HID);

  // 4) P' = exp(q.k^T) with causal mask, bf16 (max-free softmax)
  gemm_nt<bf16, false, true, false, true, false, false, false><<<dim3(8, 8, NB), 512, 0, stream>>>(
      QKV, QKV + HID, nullptr, P, HID, 3 * HID, 3 * HID, SEQL,
      (long)SEQL * 3 * HID, (long)SEQL * 3 * HID, (long)SEQL * SEQL);

  // 5) inverse row sums
  rowsum_inv<<<2048, 256, 0, stream>>>(P, RS);

  // 6) ctx = (P' @ v) / rowsum (causal K-limit, 256-granular)
  gemm_nt<bf16, false, false, true, false, true, false, false><<<dim3(4, 8, NB), 512, 0, stream>>>(
      P, VT, RS, CTX, SEQL, SEQL, SEQL, HID,
      (long)SEQL * SEQL, (long)HID * SEQL, (long)SEQL * HID);

  // 7) out = ctx @ Wo^T + bo (XCD-swizzled)
  gemm_nt<float, true, false, false, false, false, false, true><<<dim3(4, 32, 1), 512, 0, stream>>>(
      CTX, WOB, bo, out, HID, HID, HID, HID, 0, 0, 0);
}

// Round 10
// 204.505 us; speedup vs baseline: 1.0753x; 1.0753x over previous
//
#include <hip/hip_runtime.h>
#include <hip/hip_bf16.h>

typedef __bf16 bf16;
typedef __bf16 bf16x8 __attribute__((ext_vector_type(8)));
typedef __bf16 bf16x4 __attribute__((ext_vector_type(4)));
typedef float f32x4 __attribute__((ext_vector_type(4)));
typedef unsigned short ushort4v __attribute__((ext_vector_type(4)));

#define HID 1024
#define SEQL 2048
#define NB 4

#define AS1 __attribute__((address_space(1)))
#define AS3 __attribute__((address_space(3)))

// ---------------- fused fp32 -> bf16 cast (x, Wq, Wk, Wv, Wo) + bias concat ----------------
__global__ __launch_bounds__(256) void cast_all(const float* __restrict__ x,
    const float* __restrict__ Wq, const float* __restrict__ Wk,
    const float* __restrict__ Wv, const float* __restrict__ Wo,
    const float* __restrict__ bq, const float* __restrict__ bk, const float* __restrict__ bv,
    bf16* __restrict__ XB, bf16* __restrict__ WQKVB, bf16* __restrict__ WOB,
    float* __restrict__ bqkv) {
  const int b = blockIdx.x;
  if (b >= 12288) {  // 12 blocks: concat q/k/v biases [3072]
    const int i = (b - 12288) * 256 + threadIdx.x;
    bqkv[i] = (i < HID) ? bq[i] : (i < 2 * HID ? bk[i - HID] : bv[i - 2 * HID]);
    return;
  }
  const float* src; bf16* dst; long base;
  if (b < 8192) { src = x; dst = XB; base = (long)b * 256; }
  else {
    const int w = (b - 8192) >> 10, r = (b - 8192) & 1023;
    src = (w == 0) ? Wq : (w == 1) ? Wk : (w == 2) ? Wv : Wo;
    dst = (w == 3) ? WOB : WQKVB + (long)w * (HID * HID);
    base = (long)r * 256;
  }
  const long i = base + threadIdx.x;
  float4 v = reinterpret_cast<const float4*>(src)[i];
  bf16x4 o = { (bf16)v.x, (bf16)v.y, (bf16)v.z, (bf16)v.w };
  reinterpret_cast<bf16x4*>(dst)[i] = o;
}

// ---------------- NT GEMM, single-barrier counted-vmcnt pipeline, 128x128 tile ----------------
// C[M,N] = A[M,K] * B[N,K]^T. BK=32, 256 thr = 4 waves (2M x 2N), wave 64x64 (4x4 frags).
// 3 round-robin LDS buffers (48 KB -> 3 blocks/CU): compute tile t while t+1,t+2 fly;
// steady-state wait = vmcnt(4); ONE barrier per K-step so waves skew and MFMA overlaps
// other waves' ds_reads. T2 swizzle via pre-swizzled global source (gload_lds writes
// linear; read applies the same XOR). Per-wave schedule identical to the proven R4/R8
// kernel; only block composition halves (fill: 3 blk/CU, bigger grids).
// Epilogue variants: EXPP (causal mask + max-free exp), RSDIV (x bias[bz*SEQL+row]),
// QKVSC (1/32 on q cols), SWZ (XCD-chunked blockIdx, needs nwg%8==0).
template <typename OutT, bool BIAS, bool CSKIP, bool KLIM, bool EXPP, bool RSDIV, bool QKVSC, bool SWZ>
__global__ __launch_bounds__(256, 3)
void gemm_nt(const bf16* __restrict__ A, const bf16* __restrict__ B,
             const float* __restrict__ bias, OutT* __restrict__ C,
             int K, int lda, int ldb, int N, long sA, long sB, long sC) {
  int bj, bi;
  if (SWZ) {
    const int lin = blockIdx.x + gridDim.x * blockIdx.y;
    const int chunk = (gridDim.x * gridDim.y) >> 3;
    const int lg = (lin & 7) * chunk + (lin >> 3);
    bj = lg % gridDim.x; bi = lg / gridDim.x;
  } else { bj = blockIdx.x; bi = blockIdx.y; }
  const int bz = blockIdx.z;
  if (CSKIP && bj > bi) return;  // fully-masked causal 128-block
  A += (long)bz * sA + (long)bi * 128 * lda;
  B += (long)bz * sB + (long)bj * 128 * ldb;
  const int Kend = KLIM ? ((bi + 1) * 128) : K;
  const int nt = Kend >> 5;  // >= 4 for all our shapes

  __shared__ bf16 lds[3][8192];  // per buf: A 128x32 (4096 el) + B 128x32 (4096 el)

  const int t = threadIdx.x;
  const int lane = t & 63;
  const int wid = t >> 6;
  const int wr = (wid >> 1) * 64;   // wave row offset
  const int wc = (wid & 1) * 64;    // wave col offset
  const int frow = lane & 15;
  const int l = lane >> 4;  // k-granule 0..3

  const int sr = t >> 2;                               // staging row 0..63
  const int scol = (((t & 3) ^ ((t >> 3) & 3)) << 3);  // inverse-swizzled src col

  int offA[4], offB[4];
#pragma unroll
  for (int m = 0; m < 4; ++m) {
    const int r = wr + m * 16 + frow;
    offA[m] = r * 32 + ((l ^ ((r >> 1) & 3)) << 3);
  }
#pragma unroll
  for (int n = 0; n < 4; ++n) {
    const int r = wc + n * 16 + frow;
    offB[n] = 4096 + r * 32 + ((l ^ ((r >> 1) & 3)) << 3);
  }

  f32x4 acc[4][4] = {};

#define STAGE(bufi, tile)                                                                 \
  {                                                                                       \
    const int kk = (tile) << 5;                                                           \
    bf16* lb = &lds[bufi][0];                                                             \
    _Pragma("unroll") for (int j = 0; j < 2; ++j)                                         \
      __builtin_amdgcn_global_load_lds(                                                   \
          (const AS1 void*)(A + (long)(sr + j * 64) * lda + kk + scol),                   \
          (AS3 void*)(lb + j * 2048 + t * 8), 16, 0, 0);                                  \
    _Pragma("unroll") for (int j = 0; j < 2; ++j)                                         \
      __builtin_amdgcn_global_load_lds(                                                   \
          (const AS1 void*)(B + (long)(sr + j * 64) * ldb + kk + scol),                   \
          (AS3 void*)(lb + 4096 + j * 2048 + t * 8), 16, 0, 0);                           \
  }

  STAGE(0, 0);
  STAGE(1, 1);                                      // 8 loads in flight
  asm volatile("s_waitcnt vmcnt(4)" ::: "memory");  // tile 0 landed
  __builtin_amdgcn_s_barrier();
  __builtin_amdgcn_sched_barrier(0);

  int rb = 0;  // buffer holding tile tt
  for (int tt = 0; tt < nt; ++tt) {
    const bf16* lb = &lds[rb][0];
    bf16x8 af[4], bfr[4];
#pragma unroll
    for (int m = 0; m < 4; ++m) af[m] = *reinterpret_cast<const bf16x8*>(lb + offA[m]);
#pragma unroll
    for (int n = 0; n < 4; ++n) bfr[n] = *reinterpret_cast<const bf16x8*>(lb + offB[n]);
    int sb = rb + 2; if (sb >= 3) sb -= 3;
    if (tt + 2 < nt) STAGE(sb, tt + 2);  // writes buf[(tt-1)%3]: reads of it done pre-barrier
    __builtin_amdgcn_s_setprio(1);
#pragma unroll
    for (int m = 0; m < 4; ++m)
#pragma unroll
      for (int n = 0; n < 4; ++n)
        acc[m][n] = __builtin_amdgcn_mfma_f32_16x16x32_bf16(af[m], bfr[n], acc[m][n], 0, 0, 0);
    __builtin_amdgcn_s_setprio(0);
    __builtin_amdgcn_sched_barrier(0);
    // drain exactly to "tile tt+1 landed"; counted, never 0 in steady state
    if (tt + 2 < nt)      { asm volatile("s_waitcnt vmcnt(4)" ::: "memory"); }
    else if (tt + 1 < nt) { asm volatile("s_waitcnt vmcnt(0)" ::: "memory"); }
    if (tt + 1 < nt) {
      __builtin_amdgcn_s_barrier();
      __builtin_amdgcn_sched_barrier(0);
    }
    rb = (rb + 1 == 3) ? 0 : rb + 1;
  }
#undef STAGE

  // epilogue: C/D frag layout col=lane&15, row=(lane>>4)*4+rr
  const int crow = l * 4;
  const int ccol = frow;
#pragma unroll
  for (int m = 0; m < 4; ++m) {
#pragma unroll
    for (int n = 0; n < 4; ++n) {
      const int coll = wc + n * 16 + ccol;
      const int colg = bj * 128 + coll;
      const float bv = BIAS ? bias[colg] : 0.0f;
      const float sc = QKVSC ? (colg < HID ? 0.03125f : 1.0f) : 1.0f;
#pragma unroll
      for (int rr = 0; rr < 4; ++rr) {
        const int rowl = wr + m * 16 + crow + rr;
        const long row = (long)bi * 128 + rowl;
        float v = acc[m][n][rr];
        if (EXPP)  v = (colg <= row) ? __expf(v) : 0.0f;  // causal mask + max-free exp
        else       v = (v + bv) * sc;
        if (RSDIV) v *= bias[(long)bz * SEQL + row];      // 1/rowsum, per batch
        C[(long)bz * sC + row * N + colg] = (OutT)v;
      }
    }
  }
}

// ---------------- row sums of P' -> inverse (wave per row) ----------------
__global__ __launch_bounds__(256) void rowsum_inv(const bf16* __restrict__ P,
                                                  float* __restrict__ RS) {
  const int lane = threadIdx.x & 63;
  const int wid = threadIdx.x >> 6;
  const long row = (long)blockIdx.x * 4 + wid;  // 0 .. 8191
  const int i = (int)(row & (SEQL - 1));
  const bf16* src = P + row * SEQL;
  float s = 0.f;
#pragma unroll
  for (int c = 0; c < 4; ++c) {
    const int j0 = c * 512 + lane * 8;
    if (j0 <= i) {  // cols > i are exact zeros (or unread); sum needs only j<=i
      bf16x8 v = *reinterpret_cast<const bf16x8*>(src + j0);
#pragma unroll
      for (int j = 0; j < 8; ++j) s += (float)v[j];
    }
  }
#pragma unroll
  for (int off = 32; off > 0; off >>= 1) s += __shfl_xor(s, off);
  if (lane == 0) RS[row] = 1.0f / s;
}

// ---------------- bf16 64x64 tiled transpose: V[b][s][h] (stride ldv) -> VT[b][h][s] ----------------
__global__ __launch_bounds__(256) void transpose64(const bf16* __restrict__ V,
                                                   bf16* __restrict__ VT, int ldv) {
  __shared__ bf16 tile[64][72];
  const int b = blockIdx.z;
  const int s0 = blockIdx.x * 64;
  const int h0 = blockIdx.y * 64;
  const int t = threadIdx.x;
  const int r = t >> 4;
  const int c = (t & 15) * 4;
  const bf16* src = V + ((long)b * SEQL + s0) * ldv + h0;
#pragma unroll
  for (int rr = 0; rr < 4; ++rr) {
    const int row = r + rr * 16;
    *reinterpret_cast<ushort4v*>(&tile[row][c]) =
        *reinterpret_cast<const ushort4v*>(src + (long)row * ldv + c);
  }
  __syncthreads();
  bf16* dst = VT + ((long)b * HID + h0) * SEQL + s0;
#pragma unroll
  for (int rr = 0; rr < 4; ++rr) {
    const int hr = r + rr * 16;
    bf16x4 o = { tile[c + 0][hr], tile[c + 1][hr], tile[c + 2][hr], tile[c + 3][hr] };
    *reinterpret_cast<bf16x4*>(dst + (long)hr * SEQL + c) = o;
  }
}

extern "C" void kernel_launch(void* const* d_in, const int* in_sizes, int n_in,
                              void* d_out, int out_size, void* d_ws, size_t ws_size,
                              hipStream_t stream) {
  const float* x  = (const float*)d_in[0];
  const float* Wq = (const float*)d_in[1];
  const float* bq = (const float*)d_in[2];
  const float* Wk = (const float*)d_in[3];
  const float* bk = (const float*)d_in[4];
  const float* Wv = (const float*)d_in[5];
  const float* bv = (const float*)d_in[6];
  const float* Wo = (const float*)d_in[7];
  const float* bo = (const float*)d_in[8];
  float* out = (float*)d_out;

  // workspace (~136.4 MiB), lifetime-safe aliasing (as R8):
  char* ws = (char*)d_ws;
  bf16*  XB    = (bf16*)(ws);
  bf16*  WQKVB = (bf16*)(ws + 16777216L);
  float* bqkv  = (float*)(ws + 23068672L);
  bf16*  QKV   = (bf16*)(ws + 33554432L);
  bf16*  CTX   = (bf16*)(ws + 33554432L);
  bf16*  VT    = (bf16*)(ws + 83886080L);
  bf16*  WOB   = (bf16*)(ws + 100663296L);
  bf16*  P     = (bf16*)(ws + 102760448L);
  float* RS    = (float*)(ws + 136314880L);

  // 1) fused casts + bias concat
  cast_all<<<12300, 256, 0, stream>>>(x, Wq, Wk, Wv, Wo, bq, bk, bv, XB, WQKVB, WOB, bqkv);

  // 2) QKV projection: [8192,1024] x [3072,1024]^T; q-cols scaled 1/32 (XCD-swizzled)
  gemm_nt<bf16, true, false, false, false, false, true, true><<<dim3(24, 64, 1), 256, 0, stream>>>(
      XB, WQKVB, bqkv, QKV, HID, HID, HID, 3 * HID, 0, 0, 0);

  // 3) v -> vT (per batch)
  transpose64<<<dim3(SEQL / 64, HID / 64, NB), 256, 0, stream>>>(QKV + 2 * HID, VT, 3 * HID);

  // 4) P' = exp(q.k^T) with causal mask, bf16 (max-free softmax)
  gemm_nt<bf16, false, true, false, true, false, false, false><<<dim3(16, 16, NB), 256, 0, stream>>>(
      QKV, QKV + HID, nullptr, P, HID, 3 * HID, 3 * HID, SEQL,
      (long)SEQL * 3 * HID, (long)SEQL * 3 * HID, (long)SEQL * SEQL);

  // 5) inverse row sums
  rowsum_inv<<<2048, 256, 0, stream>>>(P, RS);

  // 6) ctx = (P' @ v) / rowsum (causal K-limit, 128-granular)
  gemm_nt<bf16, false, false, true, false, true, false, false><<<dim3(8, 16, NB), 256, 0, stream>>>(
      P, VT, RS, CTX, SEQL, SEQL, SEQL, HID,
      (long)SEQL * SEQL, (long)HID * SEQL, (long)SEQL * HID);

  // 7) out = ctx @ Wo^T + bo (XCD-swizzled)
  gemm_nt<float, true, false, false, false, false, false, true><<<dim3(8, 64, 1), 256, 0, stream>>>(
      CTX, WOB, bo, out, HID, HID, HID, HID, 0, 0, 0);
}

// Round 11
// 176.411 us; speedup vs baseline: 1.2466x; 1.1593x over previous
//
#include <hip/hip_runtime.h>
#include <hip/hip_bf16.h>

typedef __bf16 bf16;
typedef __bf16 bf16x8 __attribute__((ext_vector_type(8)));
typedef __bf16 bf16x4 __attribute__((ext_vector_type(4)));
typedef float f32x4 __attribute__((ext_vector_type(4)));
typedef unsigned short ushort4v __attribute__((ext_vector_type(4)));

#define HID 1024
#define SEQL 2048
#define NB 4

#define AS1 __attribute__((address_space(1)))
#define AS3 __attribute__((address_space(3)))

// ---------------- fused fp32 -> bf16 cast (x, W*) + bias concat + RS zero ----------------
__global__ __launch_bounds__(256) void cast_all(const float* __restrict__ x,
    const float* __restrict__ Wq, const float* __restrict__ Wk,
    const float* __restrict__ Wv, const float* __restrict__ Wo,
    const float* __restrict__ bq, const float* __restrict__ bk, const float* __restrict__ bv,
    bf16* __restrict__ XB, bf16* __restrict__ WQKVB, bf16* __restrict__ WOB,
    float* __restrict__ bqkv, float* __restrict__ RS) {
  const int b = blockIdx.x;
  if (b >= 12300) {  // 32 blocks: zero RS[8192] (atomic rowsum target, must be 0 each call)
    RS[(b - 12300) * 256 + threadIdx.x] = 0.0f;
    return;
  }
  if (b >= 12288) {  // 12 blocks: concat q/k/v biases [3072]
    const int i = (b - 12288) * 256 + threadIdx.x;
    bqkv[i] = (i < HID) ? bq[i] : (i < 2 * HID ? bk[i - HID] : bv[i - 2 * HID]);
    return;
  }
  const float* src; bf16* dst; long base;
  if (b < 8192) { src = x; dst = XB; base = (long)b * 256; }
  else {
    const int w = (b - 8192) >> 10, r = (b - 8192) & 1023;
    src = (w == 0) ? Wq : (w == 1) ? Wk : (w == 2) ? Wv : Wo;
    dst = (w == 3) ? WOB : WQKVB + (long)w * (HID * HID);
    base = (long)r * 256;
  }
  const long i = base + threadIdx.x;
  float4 v = reinterpret_cast<const float4*>(src)[i];
  bf16x4 o = { (bf16)v.x, (bf16)v.y, (bf16)v.z, (bf16)v.w };
  reinterpret_cast<bf16x4*>(dst)[i] = o;
}

// ---------------- NT GEMM, single-barrier counted-vmcnt pipeline (R4/R8 structure) ----------------
// C[M,N] = A[M,K] * B[N,K]^T. Tile 256x128, BK=32, 512 thr = 8 waves (4M x 2N), wave 64x64.
// 3 round-robin LDS buffers (72 KB -> 2 blocks/CU); steady-state wait vmcnt(3); one barrier
// per K-step. T2 swizzle via pre-swizzled global source. Epilogue variants:
//   EXPP : causal mask + max-free exp -> P'; per-row partial sums reduced via shfl_xor
//          butterfly (16-lane frow groups) and atomicAdd'ed into rs[bz*SEQL+row].
//   RSDIV: multiply by 1/rs[bz*SEQL+row] (PV normalization).
//   QKVSC: 1/32 on q columns. SWZ: XCD-chunked blockIdx swizzle (needs nwg%8==0).
// CSKIP dead blocks (bj > 2bi+1, fully-masked) instead perform the V->VT 64x64 tiled
// transpose (rank-indexed grid-stride over 2048 tiles), hiding it under scores compute.
template <typename OutT, bool BIAS, bool CSKIP, bool KLIM, bool EXPP, bool RSDIV, bool QKVSC, bool SWZ>
__global__ __launch_bounds__(512, 4)
void gemm_nt(const bf16* __restrict__ A, const bf16* __restrict__ B,
             const float* __restrict__ bias, OutT* __restrict__ C,
             float* __restrict__ rs, const bf16* __restrict__ vsrc, bf16* __restrict__ vdst,
             int K, int lda, int ldb, int N, long sA, long sB, long sC) {
  int bj, bi;
  if (SWZ) {
    const int lin = blockIdx.x + gridDim.x * blockIdx.y;
    const int chunk = (gridDim.x * gridDim.y) >> 3;
    const int lg = (lin & 7) * chunk + (lin >> 3);
    bj = lg % gridDim.x; bi = lg / gridDim.x;
  } else { bj = blockIdx.x; bi = blockIdx.y; }
  const int bz = blockIdx.z;
  const int t = threadIdx.x;

  __shared__ bf16 lds[3][12288];  // per buf: A 256x32 (8192 el) + B 128x32 (4096 el)

  if (CSKIP && bj > 2 * bi + 1) {
    // fully-masked causal block: do V->VT transpose slices instead (idle-slot reuse).
    bf16 (*tile)[72] = (bf16(*)[72])&lds[0][0];
    const int rank = bz * 56 + (14 * bi - bi * (bi - 1)) + (bj - (2 * bi + 2));  // 0..223
    const int r = t >> 4;          // 0..31
    const int c = (t & 15) * 4;    // 0..60
    for (int w = rank; w < 2048; w += 224) {   // 2048 = NB*(SEQL/64)*(HID/64)
      const int b = w >> 9;
      const int wi = w & 511;
      const int s0 = (wi & 31) * 64;
      const int h0 = (wi >> 5) * 64;
      const bf16* src = vsrc + ((long)b * SEQL + s0) * (3 * HID) + h0;
#pragma unroll
      for (int rr = 0; rr < 2; ++rr) {
        const int row = r + rr * 32;
        *reinterpret_cast<ushort4v*>(&tile[row][c]) =
            *reinterpret_cast<const ushort4v*>(src + (long)row * (3 * HID) + c);
      }
      __syncthreads();
      bf16* dst = vdst + ((long)b * HID + h0) * SEQL + s0;
#pragma unroll
      for (int rr = 0; rr < 2; ++rr) {
        const int hr = r + rr * 32;
        bf16x4 o = { tile[c + 0][hr], tile[c + 1][hr], tile[c + 2][hr], tile[c + 3][hr] };
        *reinterpret_cast<bf16x4*>(dst + (long)hr * SEQL + c) = o;
      }
      __syncthreads();
    }
    return;
  }

  A += (long)bz * sA + (long)bi * 256 * lda;
  B += (long)bz * sB + (long)bj * 128 * ldb;
  const int Kend = KLIM ? ((bi + 1) * 256) : K;
  const int nt = Kend >> 5;  // >= 8 for all our shapes

  const int lane = t & 63;
  const int wid = t >> 6;
  const int wr = (wid >> 1) * 64;   // wave row offset
  const int wc = (wid & 1) * 64;    // wave col offset
  const int frow = lane & 15;
  const int l = lane >> 4;  // k-granule 0..3

  const int sr = t >> 2;                               // staging row 0..127
  const int scol = (((t & 3) ^ ((t >> 3) & 3)) << 3);  // inverse-swizzled src col

  int offA[4], offB[4];
#pragma unroll
  for (int m = 0; m < 4; ++m) {
    const int r = wr + m * 16 + frow;
    offA[m] = r * 32 + ((l ^ ((r >> 1) & 3)) << 3);
  }
#pragma unroll
  for (int n = 0; n < 4; ++n) {
    const int r = wc + n * 16 + frow;
    offB[n] = 8192 + r * 32 + ((l ^ ((r >> 1) & 3)) << 3);
  }

  f32x4 acc[4][4] = {};

#define STAGE(bufi, tile_)                                                               \
  {                                                                                      \
    const int kk = (tile_) << 5;                                                         \
    bf16* lb = &lds[bufi][0];                                                            \
    __builtin_amdgcn_global_load_lds(                                                    \
        (const AS1 void*)(A + (long)sr * lda + kk + scol),                               \
        (AS3 void*)(lb + t * 8), 16, 0, 0);                                              \
    __builtin_amdgcn_global_load_lds(                                                    \
        (const AS1 void*)(A + (long)(sr + 128) * lda + kk + scol),                       \
        (AS3 void*)(lb + 4096 + t * 8), 16, 0, 0);                                       \
    __builtin_amdgcn_global_load_lds(                                                    \
        (const AS1 void*)(B + (long)sr * ldb + kk + scol),                               \
        (AS3 void*)(lb + 8192 + t * 8), 16, 0, 0);                                       \
  }

  STAGE(0, 0);
  STAGE(1, 1);                                      // 6 loads in flight
  asm volatile("s_waitcnt vmcnt(3)" ::: "memory");  // tile 0 landed
  __builtin_amdgcn_s_barrier();
  __builtin_amdgcn_sched_barrier(0);

  int rb = 0;  // buffer holding tile tt
  for (int tt = 0; tt < nt; ++tt) {
    const bf16* lb = &lds[rb][0];
    bf16x8 af[4], bfr[4];
#pragma unroll
    for (int m = 0; m < 4; ++m) af[m] = *reinterpret_cast<const bf16x8*>(lb + offA[m]);
#pragma unroll
    for (int n = 0; n < 4; ++n) bfr[n] = *reinterpret_cast<const bf16x8*>(lb + offB[n]);
    int sb = rb + 2; if (sb >= 3) sb -= 3;
    if (tt + 2 < nt) STAGE(sb, tt + 2);  // writes buf[(tt-1)%3]: reads of it done pre-barrier
    __builtin_amdgcn_s_setprio(1);
#pragma unroll
    for (int m = 0; m < 4; ++m)
#pragma unroll
      for (int n = 0; n < 4; ++n)
        acc[m][n] = __builtin_amdgcn_mfma_f32_16x16x32_bf16(af[m], bfr[n], acc[m][n], 0, 0, 0);
    __builtin_amdgcn_s_setprio(0);
    __builtin_amdgcn_sched_barrier(0);
    // drain exactly to "tile tt+1 landed"; counted, never 0 in steady state
    if (tt + 2 < nt)      { asm volatile("s_waitcnt vmcnt(3)" ::: "memory"); }
    else if (tt + 1 < nt) { asm volatile("s_waitcnt vmcnt(0)" ::: "memory"); }
    if (tt + 1 < nt) {
      __builtin_amdgcn_s_barrier();
      __builtin_amdgcn_sched_barrier(0);
    }
    rb = (rb + 1 == 3) ? 0 : rb + 1;
  }
#undef STAGE

  // epilogue: C/D frag layout col=lane&15, row=(lane>>4)*4+rr
  const int crow = l * 4;
  const int ccol = frow;
#pragma unroll
  for (int m = 0; m < 4; ++m) {
#pragma unroll
    for (int rr = 0; rr < 4; ++rr) {
      const int rowl = wr + m * 16 + crow + rr;
      const long row = (long)bi * 256 + rowl;
      const float rsv = RSDIV ? (1.0f / rs[(long)bz * SEQL + row]) : 1.0f;
      float part = 0.0f;
#pragma unroll
      for (int n = 0; n < 4; ++n) {
        const int coll = wc + n * 16 + ccol;
        const int colg = bj * 128 + coll;
        float v = acc[m][n][rr];
        if (EXPP) { v = (colg <= row) ? __expf(v) : 0.0f; part += v; }
        else {
          const float bv = BIAS ? bias[colg] : 0.0f;
          const float sc = QKVSC ? (colg < HID ? 0.03125f : 1.0f) : 1.0f;
          v = (v + bv) * sc;
        }
        if (RSDIV) v *= rsv;
        C[(long)bz * sC + row * N + colg] = (OutT)v;
      }
      if (EXPP) {
        part += __shfl_xor(part, 1);
        part += __shfl_xor(part, 2);
        part += __shfl_xor(part, 4);
        part += __shfl_xor(part, 8);
        if (frow == 0) atomicAdd(&rs[(long)bz * SEQL + row], part);
      }
    }
  }
}

extern "C" void kernel_launch(void* const* d_in, const int* in_sizes, int n_in,
                              void* d_out, int out_size, void* d_ws, size_t ws_size,
                              hipStream_t stream) {
  const float* x  = (const float*)d_in[0];
  const float* Wq = (const float*)d_in[1];
  const float* bq = (const float*)d_in[2];
  const float* Wk = (const float*)d_in[3];
  const float* bk = (const float*)d_in[4];
  const float* Wv = (const float*)d_in[5];
  const float* bv = (const float*)d_in[6];
  const float* Wo = (const float*)d_in[7];
  const float* bo = (const float*)d_in[8];
  float* out = (float*)d_out;

  // workspace (~136.4 MiB), lifetime-safe aliasing (as R8):
  char* ws = (char*)d_ws;
  bf16*  XB    = (bf16*)(ws);
  bf16*  WQKVB = (bf16*)(ws + 16777216L);
  float* bqkv  = (float*)(ws + 23068672L);
  bf16*  QKV   = (bf16*)(ws + 33554432L);
  bf16*  CTX   = (bf16*)(ws + 33554432L);
  bf16*  VT    = (bf16*)(ws + 83886080L);
  bf16*  WOB   = (bf16*)(ws + 100663296L);
  bf16*  P     = (bf16*)(ws + 102760448L);
  float* RS    = (float*)(ws + 136314880L);

  // 1) fused casts + bias concat + RS zero
  cast_all<<<12332, 256, 0, stream>>>(x, Wq, Wk, Wv, Wo, bq, bk, bv, XB, WQKVB, WOB, bqkv, RS);

  // 2) QKV projection: [8192,1024] x [3072,1024]^T; q-cols scaled 1/32 (XCD-swizzled)
  gemm_nt<bf16, true, false, false, false, false, true, true><<<dim3(24, 32, 1), 512, 0, stream>>>(
      XB, WQKVB, bqkv, QKV, nullptr, nullptr, nullptr, HID, HID, HID, 3 * HID, 0, 0, 0);

  // 3) P' = exp(q.k^T) causal, bf16, + atomic row sums; dead causal blocks do V->VT transpose
  gemm_nt<bf16, false, true, false, true, false, false, false><<<dim3(16, 8, NB), 512, 0, stream>>>(
      QKV, QKV + HID, nullptr, P, RS, QKV + 2 * HID, VT, HID, 3 * HID, 3 * HID, SEQL,
      (long)SEQL * 3 * HID, (long)SEQL * 3 * HID, (long)SEQL * SEQL);

  // 4) ctx = (P' @ v) / rowsum (causal K-limit, 256-granular)
  gemm_nt<bf16, false, false, true, false, true, false, false><<<dim3(8, 8, NB), 512, 0, stream>>>(
      P, VT, nullptr, CTX, RS, nullptr, nullptr, SEQL, SEQL, SEQL, HID,
      (long)SEQL * SEQL, (long)HID * SEQL, (long)SEQL * HID);

  // 5) out = ctx @ Wo^T + bo (XCD-swizzled)
  gemm_nt<float, true, false, false, false, false, false, true><<<dim3(8, 32, 1), 512, 0, stream>>>(
      CTX, WOB, bo, out, nullptr, nullptr, nullptr, HID, HID, HID, HID, 0, 0, 0);
}